// Round 2
// baseline (82.585 us; speedup 1.0000x reference)
//
#include <hip/hip_runtime.h>

// Problem constants (from reference)
#define NS   1000        // N_SAMPLES
#define NB   32          // batch
#define NK   27          // cluster channels
#define KP   28          // padded K (for float4)
#define HW   65536       // 256*256
// ALPHA=0.5, BETA=0.15, GAMMA=0.05, W1=10, W2=3, SHIFT=0
// sim = 10*exp(-cd/1.0 - gd/0.3) + 3*exp(-cd/0.1)

// ws layout (floats):
//   selc [NB][NS][KP]  : 32*1000*28 = 896000
//   selg [NB][NS][4]   : 128000   (offset 896000)
//   cf   [NS][2]       : 2000     (offset 1024000)
#define OFF_SELG 896000
#define OFF_CF   1024000

// gather: one thread per (n, i, ch), ch in [0,32): 0..27 -> selc (27=pad),
// 28..31 -> selg (31=pad + cf write)
__global__ void crf_gather(const float* __restrict__ guidance,
                           const float* __restrict__ clusters,
                           const int* __restrict__ coords,
                           float* __restrict__ ws) {
    int tid = blockIdx.x * 256 + threadIdx.x;
    if (tid >= NB * NS * 32) return;
    int ch = tid & 31;
    int ni = tid >> 5;
    int n = ni / NS;
    int i = ni - n * NS;
    int r = coords[i];        // coords[0][i]
    int c = coords[NS + i];   // coords[1][i]
    int pix = r * 256 + c;

    if (ch < KP) {
        float v = 0.0f;
        if (ch < NK) v = clusters[((long)n * NK + ch) * HW + pix];
        ws[(long)ni * KP + ch] = v;
    } else {
        int g = ch - KP;  // 0..3
        float v = 0.0f;
        if (g < 3) v = guidance[((long)n * 3 + g) * HW + pix];
        ws[OFF_SELG + (long)ni * 4 + g] = v;
        if (g == 3 && n == 0) {
            ws[OFF_CF + i * 2]     = (float)r;
            ws[OFF_CF + i * 2 + 1] = (float)c;
        }
    }
}

#define RA     25          // a-rows per block
#define NCHUNK 40          // NS / RA

// main: block = (n, a-chunk of 25). 256 threads, each owns 4 b-columns
// (b = i*256 + t) in registers. The a-row is wave-uniform -> compiler
// scalarizes its loads to s_load; the dot becomes v_fmac_f32 v,s,v.
__global__ __launch_bounds__(256) void crf_main(const float* __restrict__ ws,
                                                float* __restrict__ out) {
    const int bid = blockIdx.x;
    const int n = bid / NCHUNK;
    const int a0 = (bid - n * NCHUNK) * RA;
    const int t = threadIdx.x;

    const float* __restrict__ selc = ws;
    const float* __restrict__ selg = ws + OFF_SELG;
    const float* __restrict__ cf   = ws + OFF_CF;

    // per-thread b-column data in registers (112 VGPR for cb)
    float4 cb[4][7];
    float gb0[4], gb1[4], gb2[4];
    float xbr[4], xbc[4];
    #pragma unroll
    for (int i = 0; i < 4; ++i) {
        int b = i * 256 + t;
        int bc = b < NS ? b : NS - 1;   // clamp; stores predicated below
        const float4* pc = (const float4*)(selc + ((long)n * NS + bc) * KP);
        #pragma unroll
        for (int j = 0; j < 7; ++j) cb[i][j] = pc[j];
        const float* pg = selg + ((long)n * NS + bc) * 4;
        gb0[i] = pg[0]; gb1[i] = pg[1]; gb2[i] = pg[2];
        xbr[i] = cf[bc * 2]; xbc[i] = cf[bc * 2 + 1];
    }

    for (int a = 0; a < RA; ++a) {
        const int arow = n * NS + a0 + a;          // wave-uniform
        const float4* pa = (const float4*)(selc + (long)arow * KP);
        const float* pg = selg + (long)arow * 4;
        const float ga0 = pg[0], ga1 = pg[1], ga2 = pg[2];
        const float xar = cf[(a0 + a) * 2], xac = cf[(a0 + a) * 2 + 1];

        float dot[4] = {0.0f, 0.0f, 0.0f, 0.0f};
        #pragma unroll
        for (int j = 0; j < 7; ++j) {
            float4 va = pa[j];                     // uniform -> SGPRs
            #pragma unroll
            for (int i = 0; i < 4; ++i) {
                dot[i] += va.x * cb[i][j].x;
                dot[i] += va.y * cb[i][j].y;
                dot[i] += va.z * cb[i][j].z;
                dot[i] += va.w * cb[i][j].w;
            }
        }

        float* po = out + (long)arow * NS;
        #pragma unroll
        for (int i = 0; i < 4; ++i) {
            int b = i * 256 + t;
            float g0 = ga0 - gb0[i];
            float g1 = ga1 - gb1[i];
            float g2 = ga2 - gb2[i];
            float gd = g0 * g0 + g1 * g1 + g2 * g2;
            float dr = xar - xbr[i];
            float dc = xac - xbc[i];
            float cd = dr * dr + dc * dc;
            float s = 10.0f * __expf(-cd - gd * (1.0f / 0.3f))
                    +  3.0f * __expf(-10.0f * cd);
            if (b < NS) po[b] = -dot[i] * s;
        }
    }
}

extern "C" void kernel_launch(void* const* d_in, const int* in_sizes, int n_in,
                              void* d_out, int out_size, void* d_ws, size_t ws_size,
                              hipStream_t stream) {
    const float* guidance = (const float*)d_in[0];
    const float* clusters = (const float*)d_in[1];
    const int*   coords   = (const int*)d_in[2];
    float* out = (float*)d_out;
    float* ws  = (float*)d_ws;

    // gather: one thread per (n, i, channel-slot)
    {
        int total = NB * NS * 32;
        int blocks = (total + 255) / 256;
        crf_gather<<<blocks, 256, 0, stream>>>(guidance, clusters, coords, ws);
    }
    // main: one block per (n, a-chunk)
    {
        int blocks = NB * NCHUNK;
        crf_main<<<blocks, 256, 0, stream>>>(ws, out);
    }
}

// Round 3
// 78.179 us; speedup vs baseline: 1.0564x; 1.0564x over previous
//
#include <hip/hip_runtime.h>

// Problem constants (from reference)
#define NS   1000        // N_SAMPLES
#define NB   32          // batch
#define NK   27          // cluster channels
#define KP   28          // padded K (for float4)
#define HW   65536       // 256*256
// ALPHA=0.5, BETA=0.15, GAMMA=0.05, W1=10, W2=3, SHIFT=0
// sim = 10*exp(-cd/1.0 - gd/0.3) + 3*exp(-cd/0.1)

// ws layout (floats):
//   selc [NB][NS][KP]  : 896000
//   selg [NB][NS][4]   : 128000   (offset 896000)
//   cf   [NS][2]       : 2000     (offset 1024000)
#define OFF_SELG 896000
#define OFF_CF   1024000

// gather: one thread per (n, i, ch), ch in [0,32)
__global__ void crf_gather(const float* __restrict__ guidance,
                           const float* __restrict__ clusters,
                           const int* __restrict__ coords,
                           float* __restrict__ ws) {
    int tid = blockIdx.x * 256 + threadIdx.x;
    if (tid >= NB * NS * 32) return;
    int ch = tid & 31;
    int ni = tid >> 5;
    int n = ni / NS;
    int i = ni - n * NS;
    int r = coords[i];
    int c = coords[NS + i];
    int pix = r * 256 + c;

    if (ch < KP) {
        float v = 0.0f;
        if (ch < NK)
            v = __builtin_nontemporal_load(&clusters[((long)n * NK + ch) * HW + pix]);
        ws[(long)ni * KP + ch] = v;
    } else {
        int g = ch - KP;  // 0..3
        float v = 0.0f;
        if (g < 3)
            v = __builtin_nontemporal_load(&guidance[((long)n * 3 + g) * HW + pix]);
        ws[OFF_SELG + (long)ni * 4 + g] = v;
        if (g == 3 && n == 0) {
            ws[OFF_CF + i * 2]     = (float)r;
            ws[OFF_CF + i * 2 + 1] = (float)c;
        }
    }
}

#define RA     20          // a-rows per block
#define NCHUNK 50          // NS / RA

// main: block = (n, a-chunk of 20). 512 threads; thread owns b = t and t+512.
// cb tile = 56 VGPR -> target <=128 VGPR -> 4 waves/SIMD for latency hiding.
// a-row accesses are wave-uniform (scalarized). Output stores nontemporal
// (streaming, keep L2 for selc).
__global__ __launch_bounds__(512, 4) void crf_main(const float* __restrict__ ws,
                                                   float* __restrict__ out) {
    const int bid = blockIdx.x;
    const int n = bid / NCHUNK;
    const int a0 = (bid - n * NCHUNK) * RA;
    const int t = threadIdx.x;

    const float* __restrict__ selc = ws;
    const float* __restrict__ selg = ws + OFF_SELG;
    const float* __restrict__ cf   = ws + OFF_CF;

    // two b-columns per thread
    const int b0 = t;                       // always < 1000
    const int b1raw = t + 512;
    const int b1 = b1raw < NS ? b1raw : NS - 1;   // clamp loads; predicate store

    float4 cb[2][7];
    float gb0[2], gb1[2], gb2[2], xbr[2], xbc[2];
    {
        const int bs[2] = {b0, b1};
        #pragma unroll
        for (int i = 0; i < 2; ++i) {
            const float4* pc = (const float4*)(selc + ((long)n * NS + bs[i]) * KP);
            #pragma unroll
            for (int j = 0; j < 7; ++j) cb[i][j] = pc[j];
            const float* pg = selg + ((long)n * NS + bs[i]) * 4;
            gb0[i] = pg[0]; gb1[i] = pg[1]; gb2[i] = pg[2];
            xbr[i] = cf[bs[i] * 2]; xbc[i] = cf[bs[i] * 2 + 1];
        }
    }

    const bool w1 = (b1raw < NS);

    for (int a = 0; a < RA; ++a) {
        const int arow = n * NS + a0 + a;          // wave-uniform
        const float4* pa = (const float4*)(selc + (long)arow * KP);
        const float* pg = selg + (long)arow * 4;
        const float ga0 = pg[0], ga1 = pg[1], ga2 = pg[2];
        const float xar = cf[(a0 + a) * 2], xac = cf[(a0 + a) * 2 + 1];

        float dot0 = 0.0f, dot1 = 0.0f;
        #pragma unroll
        for (int j = 0; j < 7; ++j) {
            float4 va = pa[j];                     // uniform -> SGPRs
            dot0 += va.x * cb[0][j].x;  dot1 += va.x * cb[1][j].x;
            dot0 += va.y * cb[0][j].y;  dot1 += va.y * cb[1][j].y;
            dot0 += va.z * cb[0][j].z;  dot1 += va.z * cb[1][j].z;
            dot0 += va.w * cb[0][j].w;  dot1 += va.w * cb[1][j].w;
        }

        float* po = out + (long)arow * NS;

        // element 0
        {
            float g0 = ga0 - gb0[0], g1 = ga1 - gb1[0], g2 = ga2 - gb2[0];
            float gd = g0 * g0 + g1 * g1 + g2 * g2;
            float dr = xar - xbr[0], dc = xac - xbc[0];
            float cd = dr * dr + dc * dc;
            float s = 10.0f * __expf(-cd - gd * (1.0f / 0.3f))
                    +  3.0f * __expf(-10.0f * cd);
            __builtin_nontemporal_store(-dot0 * s, &po[b0]);
        }
        // element 1
        {
            float g0 = ga0 - gb0[1], g1 = ga1 - gb1[1], g2 = ga2 - gb2[1];
            float gd = g0 * g0 + g1 * g1 + g2 * g2;
            float dr = xar - xbr[1], dc = xac - xbc[1];
            float cd = dr * dr + dc * dc;
            float s = 10.0f * __expf(-cd - gd * (1.0f / 0.3f))
                    +  3.0f * __expf(-10.0f * cd);
            if (w1) __builtin_nontemporal_store(-dot1 * s, &po[b1raw]);
        }
    }
}

extern "C" void kernel_launch(void* const* d_in, const int* in_sizes, int n_in,
                              void* d_out, int out_size, void* d_ws, size_t ws_size,
                              hipStream_t stream) {
    const float* guidance = (const float*)d_in[0];
    const float* clusters = (const float*)d_in[1];
    const int*   coords   = (const int*)d_in[2];
    float* out = (float*)d_out;
    float* ws  = (float*)d_ws;

    {
        int total = NB * NS * 32;
        int blocks = (total + 255) / 256;
        crf_gather<<<blocks, 256, 0, stream>>>(guidance, clusters, coords, ws);
    }
    {
        int blocks = NB * NCHUNK;   // 1600
        crf_main<<<blocks, 512, 0, stream>>>(ws, out);
    }
}